// Round 6
// baseline (684.969 us; speedup 1.0000x reference)
//
#include <hip/hip_runtime.h>
#include <hip/hip_bf16.h>

#define B_SZ 16
#define C_IN 256
#define N_SP 2304
#define K_INT 128
#define NTILE 36  // q-tiles of 64
#define MT 32     // key/value m-tile
#define MITER 72  // N_SP / MT

typedef __attribute__((ext_vector_type(8))) short short8;
typedef __attribute__((ext_vector_type(4))) float f32x4;

// packed fp32x2 -> bf16x2 (v_cvt_pk_bf16_f32, RNE)
__device__ inline unsigned pk_bf16(float a, float b) {
  float2 f; f.x = a; f.y = b;
  __hip_bfloat162 h = __float22bfloat162_rn(f);
  unsigned u;
  __builtin_memcpy(&u, &h, sizeof(u));
  return u;
}

// ---------------------------------------------------------------------------
// Projection: Qt[b][n][k], Kt[b][n][k] (bf16), Gbf[b][c][n] = bf16(x).
// Split-k: gridDim.y = 2, each block does 64 of the 128 k-rows (both mats).
// Only the y==0 block emits Gbf (avoids duplicate writes).
// ---------------------------------------------------------------------------
__global__ __launch_bounds__(256) void proj_kernel(
    const float* __restrict__ x,
    const float* __restrict__ theta_w, const float* __restrict__ theta_b,
    const float* __restrict__ phi_w,   const float* __restrict__ phi_b,
    short* __restrict__ Qt, short* __restrict__ Kt, short* __restrict__ Gbf)
{
  __shared__ short Xl[64][264];  // [n][c], +8 pad

  const int b   = blockIdx.x / NTILE;
  const int n0  = (blockIdx.x % NTILE) * 64;
  const int kb0 = blockIdx.y * 64;
  const int t   = threadIdx.x;  // t == channel c for staging

  // ---- stage: read x row (64 fp32), packed-convert, write Gbf + LDS T ----
  {
    const float* xrow = x + ((size_t)b * C_IN + t) * N_SP + n0;
    unsigned tp[32];
#pragma unroll
    for (int i = 0; i < 16; ++i) {
      float4 v = ((const float4*)xrow)[i];
      tp[2*i]   = pk_bf16(v.x, v.y);
      tp[2*i+1] = pk_bf16(v.z, v.w);
    }
    if (blockIdx.y == 0) {
      uint4* grow = (uint4*)(Gbf + ((size_t)b * C_IN + t) * N_SP + n0);
#pragma unroll
      for (int i = 0; i < 8; ++i) {
        uint4 u; u.x = tp[4*i]; u.y = tp[4*i+1]; u.z = tp[4*i+2]; u.w = tp[4*i+3];
        grow[i] = u;
      }
    }
#pragma unroll
    for (int j = 0; j < 32; ++j) {
      Xl[2*j][t]   = (short)tp[j];
      Xl[2*j+1][t] = (short)(tp[j] >> 16);
    }
  }
  __syncthreads();

  const int wave = t >> 6, lane = t & 63;
  const int col = lane & 15, quad = lane >> 4;
  const int k = kb0 + wave * 16 + col;  // this wave's 16 k-rows

  f32x4 acc[2][4];
#pragma unroll
  for (int p = 0; p < 2; ++p)
#pragma unroll
    for (int j = 0; j < 4; ++j) {
      acc[p][j][0] = 0.f; acc[p][j][1] = 0.f;
      acc[p][j][2] = 0.f; acc[p][j][3] = 0.f;
    }

#pragma unroll
  for (int cs = 0; cs < 8; ++cs) {
    const int c0 = cs * 32;
    short8 afr[2];
#pragma unroll
    for (int p = 0; p < 2; ++p) {
      const float* W = p ? phi_w : theta_w;
      const float* wp = W + (size_t)k * C_IN + c0 + quad * 8;
      float4 w0 = ((const float4*)wp)[0];
      float4 w1 = ((const float4*)wp)[1];
      unsigned u[4];
      u[0] = pk_bf16(w0.x, w0.y); u[1] = pk_bf16(w0.z, w0.w);
      u[2] = pk_bf16(w1.x, w1.y); u[3] = pk_bf16(w1.z, w1.w);
      short8 a;
      __builtin_memcpy(&a, u, sizeof(a));
      afr[p] = a;
    }
#pragma unroll
    for (int j = 0; j < 4; ++j) {
      short8 bfr = *(const short8*)&Xl[j * 16 + col][c0 + quad * 8];
#pragma unroll
      for (int p = 0; p < 2; ++p)
        acc[p][j] = __builtin_amdgcn_mfma_f32_16x16x32_bf16(
            afr[p], bfr, acc[p][j], 0, 0, 0);
    }
  }

  // ---- epilogue: bias + transpose-store to [b][n][k] bf16 ----
#pragma unroll
  for (int p = 0; p < 2; ++p) {
    const float* bias = p ? phi_b : theta_b;
    short* dst = p ? Kt : Qt;
    const int k0 = kb0 + wave * 16 + quad * 4;
    float4 bv = *(const float4*)(bias + k0);
#pragma unroll
    for (int j = 0; j < 4; ++j) {
      const int n = n0 + j * 16 + col;
      f32x4 v = acc[p][j];
      uint2 sv;
      sv.x = pk_bf16(v[0] + bv.x, v[1] + bv.y);
      sv.y = pk_bf16(v[2] + bv.z, v[3] + bv.w);
      *(uint2*)(dst + ((size_t)b * N_SP + n) * K_INT + k0) = sv;
    }
  }
}

// ---------------------------------------------------------------------------
// Flash attention v2: ZERO barriers, zero K/G LDS. B-fragments for QK^T and
// PV are loaded directly from global (Kt is [n][k] k-contiguous; Gbf is
// [c][m] m-contiguous — both are exactly MFMA B-operand order). L1 serves
// intra-block reuse (4 waves read identical frags), L2 serves the 36 q-tile
// re-reads per batch. Only LDS: wave-private Pl for the P C->A transpose.
// ---------------------------------------------------------------------------
__global__ __launch_bounds__(256) void attn_kernel(
    const short* __restrict__ Qt, const short* __restrict__ Kt,
    const short* __restrict__ Gbf, float* __restrict__ out)
{
  __shared__ short Pl[4][16][40];  // per-wave [q][m], stride 40 (b128-aligned)

  const int b   = blockIdx.x / NTILE;
  const int qn0 = (blockIdx.x % NTILE) * 64;
  const int t = threadIdx.x;
  const int wave = t >> 6, lane = t & 63;
  const int col = lane & 15, quad = lane >> 4;

  const short* Ktb = Kt  + (size_t)b * N_SP * K_INT;
  const short* Gb  = Gbf + (size_t)b * C_IN * N_SP;

  // Q fragments in registers for the whole loop (A-operand layout)
  short8 qf[4];
  {
    const short* qb = Qt + ((size_t)b * N_SP + qn0 + wave * 16 + col) * K_INT + quad * 8;
#pragma unroll
    for (int kk = 0; kk < 4; ++kk) qf[kk] = *(const short8*)(qb + kk * 32);
  }

  f32x4 yacc[16];
#pragma unroll
  for (int i = 0; i < 16; ++i) {
    yacc[i][0] = 0.f; yacc[i][1] = 0.f; yacc[i][2] = 0.f; yacc[i][3] = 0.f;
  }
  float lsum[4] = {0.f, 0.f, 0.f, 0.f};  // per-lane partial row sums

  const float SC2 = 0.12754859f;  // (1/sqrt(128)) * log2(e)

  // per-thread fragment offsets (in shorts)
  const int kfo = col * K_INT + quad * 8;        // K-frag: row m0+jt*16+col
  const int gfo = col * N_SP + quad * 8;         // G-frag: row ct*16+col

  for (int mt = 0; mt < MITER; ++mt) {
    const int m0 = mt * MT;

    // ---- S = Q K^T : B-frags straight from global ----
    f32x4 s0, s1;
    s0[0]=0.f;s0[1]=0.f;s0[2]=0.f;s0[3]=0.f;
    s1[0]=0.f;s1[1]=0.f;s1[2]=0.f;s1[3]=0.f;
    const short* kbase = Ktb + (size_t)m0 * K_INT + kfo;
#pragma unroll
    for (int kk = 0; kk < 4; ++kk) {
      short8 kb0 = *(const short8*)(kbase + kk * 32);
      s0 = __builtin_amdgcn_mfma_f32_16x16x32_bf16(qf[kk], kb0, s0, 0, 0, 0);
      short8 kb1 = *(const short8*)(kbase + 16 * K_INT + kk * 32);
      s1 = __builtin_amdgcn_mfma_f32_16x16x32_bf16(qf[kk], kb1, s1, 0, 0, 0);
    }

    // ---- softmax-lite: p = exp2(s * c), accumulate per-lane partials ----
#pragma unroll
    for (int r = 0; r < 4; ++r) {
      float p0 = exp2f(s0[r] * SC2);
      float p1 = exp2f(s1[r] * SC2);
      Pl[wave][quad * 4 + r][col]      = (short)(pk_bf16(p0, p0) & 0xffff);
      Pl[wave][quad * 4 + r][16 + col] = (short)(pk_bf16(p1, p1) & 0xffff);
      lsum[r] += p0 + p1;
    }

    // ---- PV: Y[q][c] += P[q][m] G^T[m][c]; G-frags straight from global ----
    short8 pa = *(const short8*)&Pl[wave][col][quad * 8];
    const short* gbase = Gb + m0 + gfo;
#pragma unroll
    for (int ct = 0; ct < 16; ++ct) {
      short8 gb = *(const short8*)(gbase + ct * 16 * N_SP);
      yacc[ct] = __builtin_amdgcn_mfma_f32_16x16x32_bf16(pa, gb, yacc[ct], 0, 0, 0);
    }
  }

  // ---- final row-sum reduction (once, not per iter) ----
#pragma unroll
  for (int off = 1; off < 16; off <<= 1)
#pragma unroll
    for (int r = 0; r < 4; ++r) lsum[r] += __shfl_xor(lsum[r], off);

  float inv[4];
#pragma unroll
  for (int r = 0; r < 4; ++r) inv[r] = 1.0f / lsum[r];
  const int nb = qn0 + wave * 16 + quad * 4;
#pragma unroll
  for (int ct = 0; ct < 16; ++ct) {
    int c = ct * 16 + col;
    float4 v;
    v.x = yacc[ct][0] * inv[0]; v.y = yacc[ct][1] * inv[1];
    v.z = yacc[ct][2] * inv[2]; v.w = yacc[ct][3] * inv[3];
    *(float4*)(out + ((size_t)b * C_IN + c) * N_SP + nb) = v;
  }
}

extern "C" void kernel_launch(void* const* d_in, const int* in_sizes, int n_in,
                              void* d_out, int out_size, void* d_ws, size_t ws_size,
                              hipStream_t stream) {
  const float* x  = (const float*)d_in[0];
  const float* tw = (const float*)d_in[1];
  const float* tb = (const float*)d_in[2];
  const float* pw = (const float*)d_in[3];
  const float* pb = (const float*)d_in[4];
  float* out = (float*)d_out;

  // workspace: Qt (9.4MB) | Kt (9.4MB) | Gbf (18.9MB) = 37.75 MB total
  short* Qt  = (short*)d_ws;
  short* Kt  = Qt + (size_t)B_SZ * N_SP * K_INT;
  short* Gbf = Kt + (size_t)B_SZ * N_SP * K_INT;

  dim3 pgrid(B_SZ * NTILE, 2);
  proj_kernel<<<pgrid, 256, 0, stream>>>(x, tw, tb, pw, pb, Qt, Kt, Gbf);
  attn_kernel<<<B_SZ * NTILE, 256, 0, stream>>>(Qt, Kt, Gbf, out);
}

// Round 7
// 359.785 us; speedup vs baseline: 1.9038x; 1.9038x over previous
//
#include <hip/hip_runtime.h>
#include <hip/hip_bf16.h>

#define B_SZ 16
#define C_IN 256
#define N_SP 2304
#define K_INT 128
#define NT64 36   // tiles of 64 along n

typedef __attribute__((ext_vector_type(8))) short short8;
typedef __attribute__((ext_vector_type(4))) float f32x4;
typedef __attribute__((ext_vector_type(16))) float f32x16;

// packed fp32x2 -> bf16x2 (v_cvt_pk_bf16_f32, RNE)
__device__ inline unsigned pk_bf16(float a, float b) {
  float2 f; f.x = a; f.y = b;
  __hip_bfloat162 h = __float22bfloat162_rn(f);
  unsigned u;
  __builtin_memcpy(&u, &h, sizeof(u));
  return u;
}

// ---------------------------------------------------------------------------
// Fragment layouts (all 1KB frags, element addr = frag*512 + lane*8 + j):
//  Qf: A-frag 32x32x16. frag(b, qt=q/32, ks=k/16): elem = Q[qt*32+(lane&31)]
//      [ks*16+(lane>>5)*8+j].   Kf: identical structure (B-frag by symmetry).
//  Gf: B-frag for PV. frag(b, ct=c/32, ms=m/16): elem = G[ct*32+(lane&31)]
//      [ms*16+(lane>>5)*8+j].
// attn loads all operands at base+lane*16B: fully coalesced, L1-broadcast.
// ---------------------------------------------------------------------------

__global__ __launch_bounds__(256) void proj_kernel(
    const float* __restrict__ x,
    const float* __restrict__ theta_w, const float* __restrict__ theta_b,
    const float* __restrict__ phi_w,   const float* __restrict__ phi_b,
    short* __restrict__ Qf, short* __restrict__ Kf, short* __restrict__ Gf)
{
  __shared__ short Xc[256][72];   // [c][n] bf16 (coalesced landing pad)
  __shared__ short Xl[64][264];   // [n][c] bf16 (GEMM B-frag source)

  const int b  = blockIdx.x / NT64;
  const int n0 = (blockIdx.x % NT64) * 64;
  const int t  = threadIdx.x;

  // ---- phase A: coalesced fp32 read (16 lanes per c-row), convert ----
  {
    const int c0 = t >> 4, nn = (t & 15) * 4;
    const float* xb = x + ((size_t)b * C_IN + c0) * N_SP + n0 + nn;
#pragma unroll
    for (int i = 0; i < 16; ++i) {
      float4 v = *(const float4*)(xb + (size_t)i * 16 * N_SP);
      uint2 u; u.x = pk_bf16(v.x, v.y); u.y = pk_bf16(v.z, v.w);
      *(uint2*)&Xc[c0 + i * 16][nn] = u;
    }
  }
  __syncthreads();

  // ---- phase B: thread t owns c-row t; emit Gf (frag order) + Xl ----
  unsigned tp[32];
#pragma unroll
  for (int seg = 0; seg < 8; ++seg) {
    short8 v = *(const short8*)&Xc[t][seg * 8];
    __builtin_memcpy(&tp[seg * 4], &v, 16);
  }
  {
    short* gfb = Gf + ((size_t)(b * 8 + (t >> 5)) * 144 + (n0 >> 4)) * 512 + (t & 31) * 8;
#pragma unroll
    for (int g = 0; g < 8; ++g) {
      uint4 u; u.x = tp[4*g]; u.y = tp[4*g+1]; u.z = tp[4*g+2]; u.w = tp[4*g+3];
      *(uint4*)(gfb + (g >> 1) * 512 + (g & 1) * 256) = u;
    }
  }
#pragma unroll
  for (int j = 0; j < 32; ++j) {
    Xl[2*j][t]   = (short)tp[j];
    Xl[2*j+1][t] = (short)(tp[j] >> 16);
  }
  __syncthreads();

  // ---- GEMM: C[k][n] = W[k][:]·X[:][n], 16x16x32, wave owns 32 k-rows ----
  const int wave = t >> 6, lane = t & 63;
  const int col = lane & 15, quad = lane >> 4;

  f32x4 acc[2][2][4];
#pragma unroll
  for (int p = 0; p < 2; ++p)
#pragma unroll
    for (int kr = 0; kr < 2; ++kr)
#pragma unroll
      for (int j = 0; j < 4; ++j) {
        acc[p][kr][j][0] = 0.f; acc[p][kr][j][1] = 0.f;
        acc[p][kr][j][2] = 0.f; acc[p][kr][j][3] = 0.f;
      }

#pragma unroll
  for (int cs = 0; cs < 8; ++cs) {
    const int c0 = cs * 32;
    short8 afr[2][2];
#pragma unroll
    for (int p = 0; p < 2; ++p) {
      const float* W = p ? phi_w : theta_w;
#pragma unroll
      for (int kr = 0; kr < 2; ++kr) {
        const int k = wave * 32 + kr * 16 + col;
        const float* wp = W + (size_t)k * C_IN + c0 + quad * 8;
        float4 w0 = ((const float4*)wp)[0];
        float4 w1 = ((const float4*)wp)[1];
        unsigned u[4];
        u[0] = pk_bf16(w0.x, w0.y); u[1] = pk_bf16(w0.z, w0.w);
        u[2] = pk_bf16(w1.x, w1.y); u[3] = pk_bf16(w1.z, w1.w);
        short8 a;
        __builtin_memcpy(&a, u, sizeof(a));
        afr[p][kr] = a;
      }
    }
#pragma unroll
    for (int j = 0; j < 4; ++j) {
      short8 bfr = *(const short8*)&Xl[j * 16 + col][c0 + quad * 8];
#pragma unroll
      for (int p = 0; p < 2; ++p)
#pragma unroll
        for (int kr = 0; kr < 2; ++kr)
          acc[p][kr][j] = __builtin_amdgcn_mfma_f32_16x16x32_bf16(
              afr[p][kr], bfr, acc[p][kr][j], 0, 0, 0);
    }
  }

  // ---- epilogue: bias + store in 32x32 fragment order ----
  // value(k = wave*32+kr*16+quad*4+r, n = n0+j*16+col):
  //   ks = wave*2+kr; lane' = (n&31) + 32*(quad>>1); j7 = (quad&1)*4 + r
#pragma unroll
  for (int p = 0; p < 2; ++p) {
    const float* bias = p ? phi_b : theta_b;
    short* dst = p ? Kf : Qf;
#pragma unroll
    for (int kr = 0; kr < 2; ++kr) {
      const int ks = wave * 2 + kr;
      const int k0 = wave * 32 + kr * 16 + quad * 4;
      float4 bv = *(const float4*)(bias + k0);
#pragma unroll
      for (int j = 0; j < 4; ++j) {
        f32x4 v = acc[p][kr][j];
        uint2 sv;
        sv.x = pk_bf16(v[0] + bv.x, v[1] + bv.y);
        sv.y = pk_bf16(v[2] + bv.z, v[3] + bv.w);
        size_t addr = ((size_t)(b * 72 + (n0 >> 5) + (j >> 1)) * 8 + ks) * 512
                    + ((j & 1) * 16 + col + 32 * (quad >> 1)) * 8 + (quad & 1) * 4;
        *(uint2*)(dst + addr) = sv;
      }
    }
  }
}

// ---------------------------------------------------------------------------
// Flash attention, 32x32x16 MFMA, all operands from global in frag order.
// Block: 64 q-rows. wave = (wq = wave>>1 selects q-half, wh = wave&1 selects
// m-half for S / c-half for PV). Per 64-m step: S (8 mfma) -> exp ->
// P via double-buffered LDS transpose (1 barrier) -> PV (16 mfma).
// ---------------------------------------------------------------------------
__global__ __launch_bounds__(256) void attn_kernel(
    const short* __restrict__ Qf, const short* __restrict__ Kf,
    const short* __restrict__ Gf, float* __restrict__ out)
{
  __shared__ short Pl[2][2][32][72];  // [buf][wq][q32][m64+8pad]
  __shared__ float Ls[2][2][32];      // [wq][wh][row] partial row-sums

  const int b    = blockIdx.x / NT64;
  const int qt64 = blockIdx.x % NT64;
  const int qn0  = qt64 * 64;
  const int t = threadIdx.x, wave = t >> 6, lane = t & 63;
  const int wq = wave >> 1, wh = wave & 1;
  const int c32 = lane & 31, h = lane >> 5;

  // Q A-frags for the whole loop (8 x 1KB, coalesced)
  short8 qf[8];
  {
    const short* qb = Qf + ((size_t)(b * 72 + qt64 * 2 + wq) * 8) * 512 + lane * 8;
#pragma unroll
    for (int ks = 0; ks < 8; ++ks) qf[ks] = *(const short8*)(qb + ks * 512);
  }

  f32x16 yacc[4];
#pragma unroll
  for (int i = 0; i < 4; ++i)
#pragma unroll
    for (int r = 0; r < 16; ++r) yacc[i][r] = 0.f;
  float lsum[16];
#pragma unroll
  for (int r = 0; r < 16; ++r) lsum[r] = 0.f;

  const short* kbb = Kf + (size_t)b * 72 * 8 * 512 + lane * 8;
  const short* gbb = Gf + (size_t)b * 8 * 144 * 512 + lane * 8;
  const float SC2 = 0.12754859f;  // (1/sqrt(128)) * log2(e)

  for (int mt = 0; mt < NT64; ++mt) {
    const int buf = mt & 1;

    // ---- S = Q K^T : 32q x 32m per wave, k=128 ----
    f32x16 s;
#pragma unroll
    for (int r = 0; r < 16; ++r) s[r] = 0.f;
    const short* kf = kbb + (size_t)((mt * 2 + wh) * 8) * 512;
#pragma unroll
    for (int ks = 0; ks < 8; ++ks)
      s = __builtin_amdgcn_mfma_f32_32x32x16_bf16(
          qf[ks], *(const short8*)(kf + ks * 512), s, 0, 0, 0);

    // ---- exp + P write (C-layout -> [q][m] LDS) ----
#pragma unroll
    for (int r = 0; r < 16; ++r) {
      float p = exp2f(s[r] * SC2);
      lsum[r] += p;
      Pl[buf][wq][(r & 3) + 8 * (r >> 2) + 4 * h][wh * 32 + c32] =
          (short)(pk_bf16(p, p) & 0xffff);
    }
    __syncthreads();

    // ---- PV: Y[32q][128c] per wave over 64 m ----
#pragma unroll
    for (int ms = 0; ms < 4; ++ms) {
      short8 pa = *(const short8*)&Pl[buf][wq][c32][ms * 16 + h * 8];
      const short* gf = gbb + (size_t)((wh * 4) * 144 + mt * 4 + ms) * 512;
#pragma unroll
      for (int ct = 0; ct < 4; ++ct) {
        short8 gb = *(const short8*)(gf + (size_t)ct * 144 * 512);
        yacc[ct] = __builtin_amdgcn_mfma_f32_32x32x16_bf16(pa, gb, yacc[ct], 0, 0, 0);
      }
    }
  }

  // ---- row-sum finalize: reduce over the 32 m-cols, combine m-halves ----
#pragma unroll
  for (int off = 1; off < 32; off <<= 1)
#pragma unroll
    for (int r = 0; r < 16; ++r) lsum[r] += __shfl_xor(lsum[r], off);
  if (c32 == 0) {
#pragma unroll
    for (int r = 0; r < 16; ++r)
      Ls[wq][wh][(r & 3) + 8 * (r >> 2) + 4 * h] = lsum[r];
  }
  __syncthreads();

  float inv[16];
#pragma unroll
  for (int r = 0; r < 16; ++r) {
    int row = (r & 3) + 8 * (r >> 2) + 4 * h;
    inv[r] = 1.0f / (Ls[wq][0][row] + Ls[wq][1][row]);
  }

  // ---- store: rows (r&3 contiguous) -> float4 along n ----
#pragma unroll
  for (int g = 0; g < 4; ++g) {
    const int n = qn0 + wq * 32 + 8 * g + 4 * h;
#pragma unroll
    for (int ct = 0; ct < 4; ++ct) {
      const int c = (wh * 4 + ct) * 32 + c32;
      float4 v;
      v.x = yacc[ct][4*g+0] * inv[4*g+0];
      v.y = yacc[ct][4*g+1] * inv[4*g+1];
      v.z = yacc[ct][4*g+2] * inv[4*g+2];
      v.w = yacc[ct][4*g+3] * inv[4*g+3];
      *(float4*)(out + ((size_t)b * C_IN + c) * N_SP + n) = v;
    }
  }
}

extern "C" void kernel_launch(void* const* d_in, const int* in_sizes, int n_in,
                              void* d_out, int out_size, void* d_ws, size_t ws_size,
                              hipStream_t stream) {
  const float* x  = (const float*)d_in[0];
  const float* tw = (const float*)d_in[1];
  const float* tb = (const float*)d_in[2];
  const float* pw = (const float*)d_in[3];
  const float* pb = (const float*)d_in[4];
  float* out = (float*)d_out;

  // workspace: Qf (9.4MB) | Kf (9.4MB) | Gf (18.9MB) = 37.75 MB
  short* Qf = (short*)d_ws;
  short* Kf = Qf + (size_t)B_SZ * 72 * 8 * 512;
  short* Gf = Kf + (size_t)B_SZ * 72 * 8 * 512;

  proj_kernel<<<B_SZ * NT64, 256, 0, stream>>>(x, tw, tb, pw, pb, Qf, Kf, Gf);
  attn_kernel<<<B_SZ * NT64, 256, 0, stream>>>(Qf, Kf, Gf, out);
}